// Round 5
// baseline (5238.144 us; speedup 1.0000x reference)
//
#include <hip/hip_runtime.h>
#include <stdint.h>

#define H 512
#define B_SZ 1024
#define T_WARM 256
#define NSTEPS 64
#define TOTAL_T (T_WARM + NSTEPS)

#define RPB 16          // rows per team
#define NTEAM 64        // B_SZ / RPB
#define NCG 4           // col groups (blocks per team)
#define NBLK 256        // NTEAM * NCG == CU count, 1 block/CU
#define NTHR 512        // 8 waves, each: 16 cols x K=512

// LDS h tile: 16 rows x 512 cols x 2B, row stride 1024 B, XOR-swizzled
// byte ^= (row&3)<<5 applied to the full byte address on BOTH write and read
#define ROWB 1024

typedef __attribute__((ext_vector_type(8))) short bf16x8;
typedef __attribute__((ext_vector_type(4))) float f32x4;

static __device__ __forceinline__ ushort f2bf(float f) {
    uint32_t u = __builtin_bit_cast(uint32_t, f);
    u += 0x7FFFu + ((u >> 16) & 1u);
    return (ushort)(u >> 16);
}
static __device__ __forceinline__ float bf2f(ushort h) {
    uint32_t u = ((uint32_t)h) << 16;
    return __builtin_bit_cast(float, u);
}

__global__ void prep_kernel(const float* __restrict__ x,
                            const float* __restrict__ W_hh,
                            const float* __restrict__ b_ih,
                            const float* __restrict__ b_hh,
                            ushort* __restrict__ Wh, ushort* __restrict__ Wl,
                            float* __restrict__ bias, float* __restrict__ xT,
                            uint32_t* __restrict__ Hb0, uint32_t* __restrict__ flags) {
    int i = blockIdx.x * NTHR + threadIdx.x;     // [0, 524288)
    Hb0[i] = 0u;
    if (i < 4096) flags[i] = 0u;                  // per-(team,cg,half,slot) step counters
    if (i < H * H) {
        float w = W_hh[i];
        ushort hi = f2bf(w);
        Wh[i] = hi;
        Wl[i] = f2bf(w - bf2f(hi));
    }
    if (i < B_SZ * T_WARM) {
        int b = i & (B_SZ - 1), t = i >> 10;
        xT[t * B_SZ + b] = x[b * T_WARM + t];
    }
    if (i < H) bias[i] = b_ih[i] + b_hh[i];
}

// Two-phase step: self-K MFMA (own 128 cols, written into LDS by the previous
// epilogue — never transits L2) overlaps the remote slices' poll + L2 loads;
// barrier E; remote-K MFMA. 2 barriers/step, symmetric compute on all waves.
__global__ __launch_bounds__(NTHR, 1)
void rnn_kernel(const float* __restrict__ xT,
                const float* __restrict__ W_ih,
                const float* __restrict__ b_fc_p,
                const float* __restrict__ W_fc,
                const ushort* __restrict__ Wh_g,
                const ushort* __restrict__ Wl_g,
                const float* __restrict__ bias_g,
                uint32_t* __restrict__ Hb0, uint32_t* __restrict__ Hb1,
                uint32_t* __restrict__ flags,
                float* __restrict__ out) {
    __shared__ __align__(16) ushort h_hi[2][RPB * 512];   // ping-pong hi, 16 KB each
    __shared__ __align__(16) ushort h_lo[2][RPB * 512];   // ping-pong lo
    __shared__ __align__(16) float  w_fc_s[H];

    const int tid  = threadIdx.x;
    const int bid  = blockIdx.x;
    const int team = bid & (NTEAM - 1);   // blocks {team,+64,+128,+192}: same XCD
    const int cg   = bid >> 6;            // 0..3
    const int row0 = team * RPB;
    const int col0 = cg * 128;

    const int lane = tid & 63;
    const int wv   = tid >> 6;            // 0..7: own 16-col tile; also staged 64-col slice
    const int n    = lane & 15, q = lane >> 4;
    const bool selfw = ((wv >> 1) == cg); // this wave's slice is own block's cols

    w_fc_s[tid] = W_fc[tid];
    for (int i = tid; i < RPB * 512; i += NTHR) { h_hi[0][i] = 0; h_lo[0][i] = 0; }

    // ---- weights register-resident: wave's 16 cols x K=512, hi+lo ----
    bf16x8 Bh[16], Bl[16];
    {
        const ushort* wh = Wh_g + (col0 + wv * 16 + n) * H + q * 8;
        const ushort* wl = Wl_g + (col0 + wv * 16 + n) * H + q * 8;
        #pragma unroll
        for (int kt = 0; kt < 16; ++kt) {
            Bh[kt] = *(const bf16x8*)(wh + kt * 32);
            Bl[kt] = *(const bf16x8*)(wl + kt * 32);
        }
    }
    const float wi  = W_ih[col0 + wv * 16 + n];
    const float bj  = bias_g[col0 + wv * 16 + n];
    const float bfc = b_fc_p[0];

    // flags: [team][cg][half][slot]; producer wave wv -> (cg, wv>>2, wv&3)
    uint32_t* const myflag =
        flags + (((team * NCG + cg) * 2 + (wv >> 2)) << 2) + (wv & 3);
    // consumer: slice s=wv = cols [64s,+64) from block p=s>>1, half s&1
    const uint64_t* const pollp =
        (const uint64_t*)(flags + (((team * NCG + (wv >> 1)) * 2 + (wv & 1)) << 2));

    char* const hb0c = (char*)&h_hi[0][0];
    char* const hb1c = (char*)&h_hi[1][0];
    char* const lb0c = (char*)&h_lo[0][0];
    char* const lb1c = (char*)&h_lo[1][0];

    __syncthreads();

    for (int t = 0; t < TOTAL_T; ++t) {
        const int pp = t & 1;
        const bool roll = (t >= T_WARM);

        f32x4 xq = {0.f, 0.f, 0.f, 0.f};
        if (!roll) xq = *(const f32x4*)(xT + t * B_SZ + row0 + q * 4);

        __syncthreads();   // A: epilogue(t-1) self LDS-writes visible

        // ---- remote waves: poll + issue L2 loads (fly under phase 1) ----
        uint64_t tmp[8];
        const bool stage = (!selfw) && (t > 0);
        if (stage) {
            const uint32_t need = (uint32_t)t;
            while (true) {
                uint64_t f = __hip_atomic_load(pollp, __ATOMIC_RELAXED, __HIP_MEMORY_SCOPE_AGENT);
                if ((uint32_t)f >= need && (uint32_t)(f >> 32) >= need) break;
                __builtin_amdgcn_s_sleep(1);
            }
            const uint64_t* src = (const uint64_t*)((t & 1) ? Hb1 : Hb0);
            #pragma unroll
            for (int it = 0; it < 8; ++it) {
                int idx = it * 64 + lane;            // r = idx>>5, c = idx&31
                int r = idx >> 5, c = idx & 31;
                tmp[it] = __hip_atomic_load(src + ((row0 + r) * 256 + wv * 32 + c),
                                            __ATOMIC_RELAXED, __HIP_MEMORY_SCOPE_AGENT);
            }
        }

        // ---- phase 1: self-K MFMA, kt in [4cg, 4cg+4) ----
        const char* ha = pp ? hb1c : hb0c;
        const char* la = pp ? lb1c : lb0c;
        const int aoffs = n * ROWB + q * 16;
        const int aswz  = (n & 3) << 5;
        f32x4 a0 = {0.f, 0.f, 0.f, 0.f}, a1 = {0.f, 0.f, 0.f, 0.f};
        float yp = 0.f;
        #pragma unroll
        for (int kk = 0; kk < 4; ++kk) {
            const int kt = cg * 4 + kk;
            const int b0 = (aoffs + kt * 64) ^ aswz;
            bf16x8 ah = *(const bf16x8*)(ha + b0);
            bf16x8 al = *(const bf16x8*)(la + b0);
            f32x4& ac = (kk & 1) ? a1 : a0;
            ac = __builtin_amdgcn_mfma_f32_16x16x32_bf16(ah, Bh[kt], ac, 0, 0, 0);
            ac = __builtin_amdgcn_mfma_f32_16x16x32_bf16(al, Bh[kt], ac, 0, 0, 0);
            ac = __builtin_amdgcn_mfma_f32_16x16x32_bf16(ah, Bl[kt], ac, 0, 0, 0);
            if (roll) {
                const float* wf = &w_fc_s[kt * 32 + q * 8];
                f32x4 w0 = *(const f32x4*)wf;
                f32x4 w1 = *(const f32x4*)(wf + 4);
                #pragma unroll
                for (int j = 0; j < 4; ++j) {
                    yp += (bf2f((ushort)ah[j])     + bf2f((ushort)al[j]))     * w0[j];
                    yp += (bf2f((ushort)ah[j + 4]) + bf2f((ushort)al[j + 4])) * w1[j];
                }
            }
        }

        // ---- remote waves: unpack into LDS ----
        if (stage) {
            char* hb = pp ? hb1c : hb0c;
            char* lb = pp ? lb1c : lb0c;
            #pragma unroll
            for (int it = 0; it < 8; ++it) {
                int idx = it * 64 + lane;
                int r = idx >> 5, c = idx & 31;
                int byte = (r * ROWB + wv * 128 + c * 4) ^ ((r & 3) << 5);
                uint64_t u = tmp[it];
                uint32_t w0 = (uint32_t)u, w1 = (uint32_t)(u >> 32);
                *(uint32_t*)(hb + byte) = (w0 >> 16) | (w1 & 0xFFFF0000u);
                *(uint32_t*)(lb + byte) = (w0 & 0xFFFFu) | (w1 << 16);
            }
        }
        __syncthreads();   // E: all remote slices staged

        // ---- phase 2: remote-K MFMA (12 kt) ----
        #pragma unroll
        for (int pg = 0; pg < 4; ++pg) {
            if (pg == cg) continue;                 // uniform scalar branch
            #pragma unroll
            for (int kk = 0; kk < 4; ++kk) {
                const int kt = pg * 4 + kk;
                const int b0 = (aoffs + kt * 64) ^ aswz;
                bf16x8 ah = *(const bf16x8*)(ha + b0);
                bf16x8 al = *(const bf16x8*)(la + b0);
                f32x4& ac = (kk & 1) ? a1 : a0;
                ac = __builtin_amdgcn_mfma_f32_16x16x32_bf16(ah, Bh[kt], ac, 0, 0, 0);
                ac = __builtin_amdgcn_mfma_f32_16x16x32_bf16(al, Bh[kt], ac, 0, 0, 0);
                ac = __builtin_amdgcn_mfma_f32_16x16x32_bf16(ah, Bl[kt], ac, 0, 0, 0);
                if (roll) {
                    const float* wf = &w_fc_s[kt * 32 + q * 8];
                    f32x4 w0 = *(const f32x4*)wf;
                    f32x4 w1 = *(const f32x4*)(wf + 4);
                    #pragma unroll
                    for (int j = 0; j < 4; ++j) {
                        yp += (bf2f((ushort)ah[j])     + bf2f((ushort)al[j]))     * w0[j];
                        yp += (bf2f((ushort)ah[j + 4]) + bf2f((ushort)al[j + 4])) * w1[j];
                    }
                }
            }
        }

        // ---- y reduce + out ----
        float yfin = 0.f;
        if (roll) {
            yp += __shfl_xor(yp, 16);
            yp += __shfl_xor(yp, 32);          // all lanes: y for row n
            yfin = yp + bfc;
            if (cg == 0 && wv == 0 && lane < 16)
                out[(row0 + lane) * NSTEPS + (t - T_WARM)] = yfin;
        }

        // ---- epilogue: v -> relu -> split; global publish + self-LDS write ----
        uint32_t* hbn = (t & 1) ? Hb0 : Hb1;
        char* dh = pp ? hb0c : hb1c;        // next buffer
        char* dl = pp ? lb0c : lb1c;
        const int jcol = col0 + wv * 16 + n;
        #pragma unroll
        for (int i = 0; i < 4; ++i) {
            const int m = q * 4 + i;           // C/D: row = quad*4+reg, col = n
            const float sv = roll ? __shfl(yfin, m) : xq[i];
            float v = a0[i] + a1[i] + sv * wi + bj;
            v = fmaxf(v, 0.f);
            const ushort hb16 = f2bf(v);
            const ushort lb16 = f2bf(v - bf2f(hb16));
            const uint32_t pk = ((uint32_t)hb16 << 16) | lb16;
            __hip_atomic_store(hbn + (row0 + m) * H + jcol, pk,
                               __ATOMIC_RELAXED, __HIP_MEMORY_SCOPE_AGENT);
            // self cols straight into next LDS buffer (pair-packed u32)
            const uint32_t nb = __shfl_xor(pk, 1);
            if ((n & 1) == 0) {
                const int byte = (m * ROWB + jcol * 2) ^ ((m & 3) << 5);
                *(uint32_t*)(dh + byte) = (pk >> 16)     | (nb & 0xFFFF0000u);
                *(uint32_t*)(dl + byte) = (pk & 0xFFFFu) | (nb << 16);
            }
        }
        asm volatile("s_waitcnt vmcnt(0)" ::: "memory");
        if (lane == 0)
            __hip_atomic_store(myflag, (uint32_t)(t + 1),
                               __ATOMIC_RELAXED, __HIP_MEMORY_SCOPE_AGENT);
    }
}

extern "C" void kernel_launch(void* const* d_in, const int* in_sizes, int n_in,
                              void* d_out, int out_size, void* d_ws, size_t ws_size,
                              hipStream_t stream) {
    const float* x    = (const float*)d_in[0];
    const float* W_ih = (const float*)d_in[1];
    const float* W_hh = (const float*)d_in[2];
    const float* b_ih = (const float*)d_in[3];
    const float* b_hh = (const float*)d_in[4];
    const float* W_fc = (const float*)d_in[5];
    const float* b_fc = (const float*)d_in[6];
    float* out = (float*)d_out;

    // ws carve (bytes): Wh 512K | Wl 512K | bias 4K | xT 1M | Hb0 2M | Hb1 2M | flags 16K
    uint8_t* w = (uint8_t*)d_ws;
    ushort*   Wh    = (ushort*)(w);
    ushort*   Wl    = (ushort*)(w + 524288);
    float*    bias  = (float*)(w + 1048576);
    float*    xT    = (float*)(w + 1052672);
    uint32_t* Hb0   = (uint32_t*)(w + 2101248);
    uint32_t* Hb1   = (uint32_t*)(w + 4198400);
    uint32_t* flags = (uint32_t*)(w + 6295552);

    prep_kernel<<<1024, NTHR, 0, stream>>>(x, W_hh, b_ih, b_hh, Wh, Wl, bias, xT, Hb0, flags);
    rnn_kernel<<<NBLK, NTHR, 0, stream>>>(xT, W_ih, b_fc, W_fc, Wh, Wl, bias, Hb0, Hb1, flags, out);
}

// Round 6
// 1204.561 us; speedup vs baseline: 4.3486x; 4.3486x over previous
//
#include <hip/hip_runtime.h>
#include <stdint.h>

#define H 512
#define B_SZ 1024
#define T_WARM 256
#define NSTEPS 64
#define TOTAL_T (T_WARM + NSTEPS)

#define RPB 16          // rows per team
#define NTEAM 64        // B_SZ / RPB
#define NCG 4           // col groups (blocks per team)
#define NBLK 256        // NTEAM * NCG == CU count, 1 block/CU
#define NTHR 512        // 8 waves, each: 16 cols x K=512

// LDS h tile: 16 rows x 512 cols x 2B, row stride 1024 B, XOR-swizzled
// byte ^= (row&3)<<5 applied to the full byte address on BOTH write and read
#define ROWB 1024

typedef __attribute__((ext_vector_type(8))) short bf16x8;
typedef __attribute__((ext_vector_type(4))) float f32x4;

static __device__ __forceinline__ ushort f2bf(float f) {
    uint32_t u = __builtin_bit_cast(uint32_t, f);
    u += 0x7FFFu + ((u >> 16) & 1u);
    return (ushort)(u >> 16);
}
static __device__ __forceinline__ float bf2f(ushort h) {
    uint32_t u = ((uint32_t)h) << 16;
    return __builtin_bit_cast(float, u);
}

__global__ void prep_kernel(const float* __restrict__ x,
                            const float* __restrict__ W_hh,
                            const float* __restrict__ b_ih,
                            const float* __restrict__ b_hh,
                            ushort* __restrict__ Wh, ushort* __restrict__ Wl,
                            float* __restrict__ bias, float* __restrict__ xT,
                            uint32_t* __restrict__ Hb0, uint32_t* __restrict__ flags) {
    int i = blockIdx.x * NTHR + threadIdx.x;     // [0, 524288)
    Hb0[i] = 0u;
    if (i < 4096) flags[i] = 0u;                  // per-(team,cg,half,slot) step counters
    if (i < H * H) {
        float w = W_hh[i];
        ushort hi = f2bf(w);
        Wh[i] = hi;
        Wl[i] = f2bf(w - bf2f(hi));
    }
    if (i < B_SZ * T_WARM) {
        int b = i & (B_SZ - 1), t = i >> 10;
        xT[t * B_SZ + b] = x[b * T_WARM + t];
    }
    if (i < H) bias[i] = b_ih[i] + b_hh[i];
}

// Two-phase step: self-K MFMA (own 128 cols, written into LDS by the previous
// epilogue — never transits L2) overlaps the remote slices' poll + L2 loads;
// barrier E; remote-K MFMA. Weight registers are ROTATED: slot i holds global
// k-tile (cg*4+i)&15, so ALL register indices are compile-time (R5 lesson:
// runtime-indexed register arrays get demoted -> 10.8 GB refetch).
__global__ __launch_bounds__(NTHR, 1)
void rnn_kernel(const float* __restrict__ xT,
                const float* __restrict__ W_ih,
                const float* __restrict__ b_fc_p,
                const float* __restrict__ W_fc,
                const ushort* __restrict__ Wh_g,
                const ushort* __restrict__ Wl_g,
                const float* __restrict__ bias_g,
                uint32_t* __restrict__ Hb0, uint32_t* __restrict__ Hb1,
                uint32_t* __restrict__ flags,
                float* __restrict__ out) {
    __shared__ __align__(16) ushort h_hi[2][RPB * 512];   // ping-pong hi, 16 KB each
    __shared__ __align__(16) ushort h_lo[2][RPB * 512];   // ping-pong lo
    __shared__ __align__(16) float  w_fc_s[H];

    const int tid  = threadIdx.x;
    const int bid  = blockIdx.x;
    const int team = bid & (NTEAM - 1);   // blocks {team,+64,+128,+192}: same XCD
    const int cg   = bid >> 6;            // 0..3
    const int row0 = team * RPB;
    const int col0 = cg * 128;

    const int lane = tid & 63;
    const int wv   = tid >> 6;            // 0..7: own 16-col tile; also staged 64-col slice
    const int n    = lane & 15, q = lane >> 4;
    const bool selfw = ((wv >> 1) == cg); // this wave's slice is own block's cols

    w_fc_s[tid] = W_fc[tid];
    for (int i = tid; i < RPB * 512; i += NTHR) { h_hi[0][i] = 0; h_lo[0][i] = 0; }

    // ---- weights register-resident, ROTATED: slot i <-> global kt (cg*4+i)&15 ----
    bf16x8 Bh[16], Bl[16];
    {
        const ushort* wh = Wh_g + (col0 + wv * 16 + n) * H + q * 8;
        const ushort* wl = Wl_g + (col0 + wv * 16 + n) * H + q * 8;
        #pragma unroll
        for (int i = 0; i < 16; ++i) {
            const int ktg = (cg * 4 + i) & 15;
            Bh[i] = *(const bf16x8*)(wh + ktg * 32);
            Bl[i] = *(const bf16x8*)(wl + ktg * 32);
        }
    }
    const float wi  = W_ih[col0 + wv * 16 + n];
    const float bj  = bias_g[col0 + wv * 16 + n];
    const float bfc = b_fc_p[0];

    // flags: [team][cg][half][slot]; producer wave wv -> (cg, wv>>2, wv&3)
    uint32_t* const myflag =
        flags + (((team * NCG + cg) * 2 + (wv >> 2)) << 2) + (wv & 3);
    // consumer: slice s=wv = cols [64s,+64) from block p=s>>1, half s&1
    const uint64_t* const pollp =
        (const uint64_t*)(flags + (((team * NCG + (wv >> 1)) * 2 + (wv & 1)) << 2));

    char* const hb0c = (char*)&h_hi[0][0];
    char* const hb1c = (char*)&h_hi[1][0];
    char* const lb0c = (char*)&h_lo[0][0];
    char* const lb1c = (char*)&h_lo[1][0];

    __syncthreads();

    for (int t = 0; t < TOTAL_T; ++t) {
        const int pp = t & 1;
        const bool roll = (t >= T_WARM);

        f32x4 xq = {0.f, 0.f, 0.f, 0.f};
        if (!roll) xq = *(const f32x4*)(xT + t * B_SZ + row0 + q * 4);

        __syncthreads();   // A: epilogue(t-1) self LDS-writes visible

        // ---- remote waves: poll + issue L2 loads (fly under phase 1) ----
        uint64_t tmp[8];
        const bool stage = (!selfw) && (t > 0);
        if (stage) {
            const uint32_t need = (uint32_t)t;
            while (true) {
                uint64_t f = __hip_atomic_load(pollp, __ATOMIC_RELAXED, __HIP_MEMORY_SCOPE_AGENT);
                if ((uint32_t)f >= need && (uint32_t)(f >> 32) >= need) break;
                __builtin_amdgcn_s_sleep(1);
            }
            const uint64_t* src = (const uint64_t*)((t & 1) ? Hb1 : Hb0);
            #pragma unroll
            for (int it = 0; it < 8; ++it) {
                int idx = it * 64 + lane;            // r = idx>>5, c = idx&31
                int r = idx >> 5, c = idx & 31;
                tmp[it] = __hip_atomic_load(src + ((row0 + r) * 256 + wv * 32 + c),
                                            __ATOMIC_RELAXED, __HIP_MEMORY_SCOPE_AGENT);
            }
        }

        // ---- phase 1: self-K MFMA — register slots 0..3 (compile-time) ----
        const char* ha = pp ? hb1c : hb0c;
        const char* la = pp ? lb1c : lb0c;
        const int aoffs = n * ROWB + q * 16;
        const int aswz  = (n & 3) << 5;
        f32x4 a0 = {0.f, 0.f, 0.f, 0.f}, a1 = {0.f, 0.f, 0.f, 0.f};
        float yp = 0.f;
        #pragma unroll
        for (int kk = 0; kk < 4; ++kk) {
            const int ktg = cg * 4 + kk;             // runtime ADDRESS only
            const int b0 = (aoffs + ktg * 64) ^ aswz;
            bf16x8 ah = *(const bf16x8*)(ha + b0);
            bf16x8 al = *(const bf16x8*)(la + b0);
            f32x4& ac = (kk & 1) ? a1 : a0;
            ac = __builtin_amdgcn_mfma_f32_16x16x32_bf16(ah, Bh[kk], ac, 0, 0, 0);
            ac = __builtin_amdgcn_mfma_f32_16x16x32_bf16(al, Bh[kk], ac, 0, 0, 0);
            ac = __builtin_amdgcn_mfma_f32_16x16x32_bf16(ah, Bl[kk], ac, 0, 0, 0);
            if (roll) {
                const float* wf = &w_fc_s[ktg * 32 + q * 8];
                f32x4 w0 = *(const f32x4*)wf;
                f32x4 w1 = *(const f32x4*)(wf + 4);
                #pragma unroll
                for (int j = 0; j < 4; ++j) {
                    yp += (bf2f((ushort)ah[j])     + bf2f((ushort)al[j]))     * w0[j];
                    yp += (bf2f((ushort)ah[j + 4]) + bf2f((ushort)al[j + 4])) * w1[j];
                }
            }
        }

        // ---- remote waves: unpack into LDS ----
        if (stage) {
            char* hb = pp ? hb1c : hb0c;
            char* lb = pp ? lb1c : lb0c;
            #pragma unroll
            for (int it = 0; it < 8; ++it) {
                int idx = it * 64 + lane;
                int r = idx >> 5, c = idx & 31;
                int byte = (r * ROWB + wv * 128 + c * 4) ^ ((r & 3) << 5);
                uint64_t u = tmp[it];
                uint32_t w0 = (uint32_t)u, w1 = (uint32_t)(u >> 32);
                *(uint32_t*)(hb + byte) = (w0 >> 16) | (w1 & 0xFFFF0000u);
                *(uint32_t*)(lb + byte) = (w0 & 0xFFFFu) | (w1 << 16);
            }
        }
        __syncthreads();   // E: all remote slices staged

        // ---- phase 2: remote-K MFMA — register slots 4..15 (compile-time) ----
        #pragma unroll
        for (int i = 4; i < 16; ++i) {
            const int ktg = (cg * 4 + i) & 15;       // runtime ADDRESS only
            const int b0 = (aoffs + ktg * 64) ^ aswz;
            bf16x8 ah = *(const bf16x8*)(ha + b0);
            bf16x8 al = *(const bf16x8*)(la + b0);
            f32x4& ac = (i & 1) ? a1 : a0;
            ac = __builtin_amdgcn_mfma_f32_16x16x32_bf16(ah, Bh[i], ac, 0, 0, 0);
            ac = __builtin_amdgcn_mfma_f32_16x16x32_bf16(al, Bh[i], ac, 0, 0, 0);
            ac = __builtin_amdgcn_mfma_f32_16x16x32_bf16(ah, Bl[i], ac, 0, 0, 0);
            if (roll) {
                const float* wf = &w_fc_s[ktg * 32 + q * 8];
                f32x4 w0 = *(const f32x4*)wf;
                f32x4 w1 = *(const f32x4*)(wf + 4);
                #pragma unroll
                for (int j = 0; j < 4; ++j) {
                    yp += (bf2f((ushort)ah[j])     + bf2f((ushort)al[j]))     * w0[j];
                    yp += (bf2f((ushort)ah[j + 4]) + bf2f((ushort)al[j + 4])) * w1[j];
                }
            }
        }

        // ---- y reduce + out ----
        float yfin = 0.f;
        if (roll) {
            yp += __shfl_xor(yp, 16);
            yp += __shfl_xor(yp, 32);          // all lanes: y for row n
            yfin = yp + bfc;
            if (cg == 0 && wv == 0 && lane < 16)
                out[(row0 + lane) * NSTEPS + (t - T_WARM)] = yfin;
        }

        // ---- epilogue: v -> relu -> split; global publish + self-LDS write ----
        uint32_t* hbn = (t & 1) ? Hb0 : Hb1;
        char* dh = pp ? hb0c : hb1c;        // next buffer
        char* dl = pp ? lb0c : lb1c;
        const int jcol = col0 + wv * 16 + n;
        #pragma unroll
        for (int i = 0; i < 4; ++i) {
            const int m = q * 4 + i;           // C/D: row = quad*4+reg, col = n
            const float sv = roll ? __shfl(yfin, m) : xq[i];
            float v = a0[i] + a1[i] + sv * wi + bj;
            v = fmaxf(v, 0.f);
            const ushort hb16 = f2bf(v);
            const ushort lb16 = f2bf(v - bf2f(hb16));
            const uint32_t pk = ((uint32_t)hb16 << 16) | lb16;
            __hip_atomic_store(hbn + (row0 + m) * H + jcol, pk,
                               __ATOMIC_RELAXED, __HIP_MEMORY_SCOPE_AGENT);
            // self cols straight into next LDS buffer (pair-packed u32)
            const uint32_t nb = __shfl_xor(pk, 1);
            if ((n & 1) == 0) {
                const int byte = (m * ROWB + jcol * 2) ^ ((m & 3) << 5);
                *(uint32_t*)(dh + byte) = (pk >> 16)     | (nb & 0xFFFF0000u);
                *(uint32_t*)(dl + byte) = (pk & 0xFFFFu) | (nb << 16);
            }
        }
        asm volatile("s_waitcnt vmcnt(0)" ::: "memory");
        if (lane == 0)
            __hip_atomic_store(myflag, (uint32_t)(t + 1),
                               __ATOMIC_RELAXED, __HIP_MEMORY_SCOPE_AGENT);
    }
}

extern "C" void kernel_launch(void* const* d_in, const int* in_sizes, int n_in,
                              void* d_out, int out_size, void* d_ws, size_t ws_size,
                              hipStream_t stream) {
    const float* x    = (const float*)d_in[0];
    const float* W_ih = (const float*)d_in[1];
    const float* W_hh = (const float*)d_in[2];
    const float* b_ih = (const float*)d_in[3];
    const float* b_hh = (const float*)d_in[4];
    const float* W_fc = (const float*)d_in[5];
    const float* b_fc = (const float*)d_in[6];
    float* out = (float*)d_out;

    // ws carve (bytes): Wh 512K | Wl 512K | bias 4K | xT 1M | Hb0 2M | Hb1 2M | flags 16K
    uint8_t* w = (uint8_t*)d_ws;
    ushort*   Wh    = (ushort*)(w);
    ushort*   Wl    = (ushort*)(w + 524288);
    float*    bias  = (float*)(w + 1048576);
    float*    xT    = (float*)(w + 1052672);
    uint32_t* Hb0   = (uint32_t*)(w + 2101248);
    uint32_t* Hb1   = (uint32_t*)(w + 4198400);
    uint32_t* flags = (uint32_t*)(w + 6295552);

    prep_kernel<<<1024, NTHR, 0, stream>>>(x, W_hh, b_ih, b_hh, Wh, Wl, bias, xT, Hb0, flags);
    rnn_kernel<<<NBLK, NTHR, 0, stream>>>(xT, W_ih, b_fc, W_fc, Wh, Wl, bias, Hb0, Hb1, flags, out);
}